// Round 5
// baseline (741.029 us; speedup 1.0000x reference)
//
#include <hip/hip_runtime.h>

typedef unsigned short u16;
typedef __attribute__((ext_vector_type(4))) float f32x4;
typedef __attribute__((ext_vector_type(16))) float f32x16;
typedef __attribute__((ext_vector_type(8))) short s16x8;
typedef __attribute__((ext_vector_type(2))) unsigned int u32x2v;

#define CEXP 0.12751742929f  // log2(e)/sqrt(128)

static __device__ __forceinline__ u16 f2bf(float x) {
  unsigned u = __float_as_uint(x);
  u = u + 0x7fffu + ((u >> 16) & 1u);
  return (u16)(u >> 16);
}
static __device__ __forceinline__ unsigned cvtpk(float a, float b) {
  unsigned r;
  asm("v_cvt_pk_bf16_f32 %0, %1, %2" : "=v"(r) : "v"(a), "v"(b));
  return r;
}
static __device__ __forceinline__ u32x2v pswap(unsigned a, unsigned b) {
  return __builtin_amdgcn_permlane32_swap(a, b, false, false);
}
static __device__ __forceinline__ f32x4 fzero() { f32x4 z; z[0]=0.f; z[1]=0.f; z[2]=0.f; z[3]=0.f; return z; }
static __device__ __forceinline__ f32x4 mfma16(s16x8 a, s16x8 b, f32x4 c) {
  return __builtin_amdgcn_mfma_f32_16x16x32_bf16(a, b, c, 0, 0, 0);
}
static __device__ __forceinline__ f32x16 mfma32(s16x8 a, s16x8 b, f32x16 c) {
  return __builtin_amdgcn_mfma_f32_32x32x16_bf16(a, b, c, 0, 0, 0);
}
static __device__ __forceinline__ void gld16(const void* g, void* l) {
  __builtin_amdgcn_global_load_lds((const __attribute__((address_space(1))) void*)g,
                                   (__attribute__((address_space(3))) void*)l, 16, 0, 0);
}

// ---------------- fp32 -> bf16 convert, dst index = i + (i>>lg)<<lg ----------------
__global__ void cvt_kernel(const float* __restrict__ s, u16* __restrict__ d, int n4, int lg) {
  int stride = gridDim.x * blockDim.x;
  for (int i4 = blockIdx.x * blockDim.x + threadIdx.x; i4 < n4; i4 += stride) {
    int i = i4 * 4;
    float4 v = *reinterpret_cast<const float4*>(s + i);
    size_t di = (size_t)i + ((size_t)(i >> lg) << lg);
    ushort4 o;
    o.x = f2bf(v.x); o.y = f2bf(v.y); o.z = f2bf(v.z); o.w = f2bf(v.w);
    *reinterpret_cast<ushort4*>(d + di) = o;
  }
}

// ---------------- V transpose: [bh][2048][128] -> Vt [bh][128][4096] ----------------
__global__ void transpose_past_v(const float* __restrict__ src, u16* __restrict__ dst) {
  __shared__ u16 tile[64 * 138];
  int bh = blockIdx.y, pt = blockIdx.x;
  const float* s = src + ((size_t)bh * 2048 + (size_t)pt * 64) * 128;
  int t = threadIdx.x;
#pragma unroll
  for (int it = 0; it < 8; ++it) {
    int idx = it * 1024 + t * 4;
    int row = idx >> 7, col = idx & 127;
    float4 v = *reinterpret_cast<const float4*>(s + idx);
    u16* d = &tile[row * 138 + col];
    d[0] = f2bf(v.x); d[1] = f2bf(v.y); d[2] = f2bf(v.z); d[3] = f2bf(v.w);
  }
  __syncthreads();
  size_t dbase = (size_t)bh * 128 * 4096 + (size_t)pt * 64;
#pragma unroll
  for (int it = 0; it < 32; ++it) {
    int o = it * 256 + t;
    int dd = o >> 6, pos = o & 63;
    dst[dbase + (size_t)dd * 4096 + pos] = tile[pos * 138 + dd];
  }
}

__global__ void transpose_new_v(const u16* __restrict__ src, u16* __restrict__ dst) {
  __shared__ u16 tile[64 * 138];
  int bh = blockIdx.y, pt = blockIdx.x;
  const u16* s = src + ((size_t)bh * 2048 + (size_t)pt * 64) * 128;
  int t = threadIdx.x;
#pragma unroll
  for (int it = 0; it < 8; ++it) {
    int idx = it * 1024 + t * 4;
    int row = idx >> 7, col = idx & 127;
    ushort4 v = *reinterpret_cast<const ushort4*>(s + idx);
    u16* d = &tile[row * 138 + col];
    d[0] = v.x; d[1] = v.y; d[2] = v.z; d[3] = v.w;
  }
  __syncthreads();
  size_t dbase = (size_t)bh * 128 * 4096 + 2048 + (size_t)pt * 64;
#pragma unroll
  for (int it = 0; it < 32; ++it) {
    int o = it * 256 + t;
    int dd = o >> 6, pos = o & 63;
    dst[dbase + (size_t)dd * 4096 + pos] = tile[pos * 138 + dd];
  }
}

// ---------------- 128x128 GEMM core, counted-vmcnt pipeline ----------------
static __device__ __forceinline__ void gemm_core(const u16* __restrict__ A, const u16* __restrict__ Wn,
                                                 int m0, char* ldsb, f32x4 (&acc)[4][4]) {
  const int tid = threadIdx.x;
  const int w = tid >> 6, lane = tid & 63, g = lane >> 4, ln = lane & 15;
#pragma unroll
  for (int mi = 0; mi < 4; ++mi)
#pragma unroll
    for (int ni = 0; ni < 4; ++ni) acc[mi][ni] = fzero();

  auto stage = [&](int buf, int k0) {
#pragma unroll
    for (int i = 0; i < 2; ++i) {
      int c = w * 2 + i;
      int p = c * 1024 + lane * 16;
      int row = p >> 6;
      int colb = (p & 63) ^ ((row & 3) << 4);
      const u16* sa = A + (size_t)(m0 + row) * 2048 + k0 + (colb >> 1);
      const u16* sw = Wn + (size_t)row * 2048 + k0 + (colb >> 1);
      char* da = ldsb + buf * 16384 + c * 1024;
      gld16(sa, da);
      gld16(sw, da + 8192);
    }
  };
  stage(0, 0);
  const int wr = w >> 1, wc = w & 1;
  for (int kt = 0; kt < 64; ++kt) {
    int cur = kt & 1;
    if (kt < 63) {
      stage(cur ^ 1, (kt + 1) * 32);
      asm volatile("s_waitcnt vmcnt(4)\n\ts_barrier" ::: "memory");  // tile kt landed; kt+1 in flight
    } else {
      asm volatile("s_waitcnt vmcnt(0)\n\ts_barrier" ::: "memory");
    }
    const char* bp = ldsb + cur * 16384;
    s16x8 af[4], bw[4];
#pragma unroll
    for (int mi = 0; mi < 4; ++mi) {
      int row = wr * 64 + mi * 16 + ln;
      int lin = row * 64 + g * 16;
      af[mi] = *reinterpret_cast<const s16x8*>(bp + (lin ^ ((row & 3) << 4)));
    }
#pragma unroll
    for (int ni = 0; ni < 4; ++ni) {
      int row = wc * 64 + ni * 16 + ln;
      int lin = row * 64 + g * 16;
      bw[ni] = *reinterpret_cast<const s16x8*>(bp + 8192 + (lin ^ ((row & 3) << 4)));
    }
#pragma unroll
    for (int mi = 0; mi < 4; ++mi)
#pragma unroll
      for (int ni = 0; ni < 4; ++ni)
        acc[mi][ni] = mfma16(af[mi], bw[ni], acc[mi][ni]);
    asm volatile("s_waitcnt lgkmcnt(0)\n\ts_barrier" ::: "memory");  // reads of cur done; no vm drain
  }
}

// ---------------- fused QKV projection ----------------
__global__ __launch_bounds__(256, 3) void qkv_gemm(const u16* __restrict__ xb,
    const u16* __restrict__ wq, const u16* __restrict__ wk, const u16* __restrict__ wv,
    const float* __restrict__ bq, const float* __restrict__ bk, const float* __restrict__ bv,
    u16* __restrict__ outq, u16* __restrict__ kc, u16* __restrict__ outv) {
  __shared__ char ldsb[32768];
  int m0 = blockIdx.x * 128;
  int ny = blockIdx.y;
  int wsel = ny >> 4, n0 = (ny & 15) * 128;
  const u16* W; const float* bias; u16* dst; int lrow, off;
  if (wsel == 0)      { W = wq; bias = bq; dst = outq; lrow = 2048; off = 0; }
  else if (wsel == 1) { W = wk; bias = bk; dst = kc;   lrow = 4096; off = 2048; }
  else                { W = wv; bias = bv; dst = outv; lrow = 2048; off = 0; }
  f32x4 acc[4][4];
  gemm_core(xb, W + (size_t)n0 * 2048, m0, ldsb, acc);
  const int tid = threadIdx.x, w = tid >> 6, lane = tid & 63, g = lane >> 4, ln = lane & 15;
  const int wr = w >> 1, wc = w & 1;
#pragma unroll
  for (int ni = 0; ni < 4; ++ni) {
    int j = n0 + wc * 64 + ni * 16 + ln;
    float bcol = bias[j];
    int h = j >> 7, hd = j & 127;
#pragma unroll
    for (int mi = 0; mi < 4; ++mi) {
#pragma unroll
      for (int r = 0; r < 4; ++r) {
        int rowg = m0 + wr * 64 + mi * 16 + g * 4 + r;
        int b = rowg >> 11, s = rowg & 2047;
        float val = acc[mi][ni][r] + bcol;
        dst[((size_t)(b * 16 + h) * lrow + off + s) * 128 + hd] = f2bf(val);
      }
    }
  }
}

// ---------------- output projection ----------------
__global__ __launch_bounds__(256, 3) void proj_gemm(const u16* __restrict__ ao, const u16* __restrict__ wo,
    const float* __restrict__ bo, float* __restrict__ out) {
  __shared__ char ldsb[32768];
  int m0 = blockIdx.x * 128, n0 = blockIdx.y * 128;
  f32x4 acc[4][4];
  gemm_core(ao, wo + (size_t)n0 * 2048, m0, ldsb, acc);
  const int tid = threadIdx.x, w = tid >> 6, lane = tid & 63, g = lane >> 4, ln = lane & 15;
  const int wr = w >> 1, wc = w & 1;
#pragma unroll
  for (int ni = 0; ni < 4; ++ni) {
    int j = n0 + wc * 64 + ni * 16 + ln;
    float bcol = bo[j];
#pragma unroll
    for (int mi = 0; mi < 4; ++mi) {
#pragma unroll
      for (int r = 0; r < 4; ++r) {
        int rowg = m0 + wr * 64 + mi * 16 + g * 4 + r;
        out[(size_t)rowg * 2048 + j] = acc[mi][ni][r] + bcol;
      }
    }
  }
}

// ---------------- flash attention (32x32 MFMA, K LDS-dbuf + reg-staged V, 48KB LDS) ----------------
// grid (32, 16): x = bh (XCD locality), y -> qbk remapped for complementary pairing.
// Pipeline per iter t: issue V(t+1)->regs, K(t+1)->LDS; vmcnt(8) drains K(t) only.
// End of iter: barrier after all reads; ds_write V(t+1) (auto vmcnt(4) leaves K(t+1) in flight).
__global__ __launch_bounds__(256, 3) void attn_kernel(const u16* __restrict__ Qb,
    const u16* __restrict__ Kc, const u16* __restrict__ Vt, u16* __restrict__ Ao) {
  __shared__ char lds[49152];  // K dbuf 2x16KB @0, V 16KB @32768
  const int tid = threadIdx.x, w = tid >> 6, lane = tid & 63;
  const int hi = lane >> 5, l5 = lane & 31;
  const int bh = blockIdx.x;
  const int qy = blockIdx.y;
  const int qbk = (qy & 8) ? (15 - (qy & 7)) : qy;
  const int b = bh >> 4, h = bh & 15;
  const u16* Qbh = Qb + (size_t)bh * 2048 * 128;
  const u16* Kbh = Kc + (size_t)bh * 4096 * 128;
  const u16* Vbh = Vt + (size_t)bh * 128 * 4096;

  const int qrow0 = qbk * 128 + w * 32;
  const int qp = 2048 + qrow0 + l5;
  const int qpmin = 2048 + qrow0;
  const int ntiles = (2048 + qbk * 128 + 128) >> 6;

  s16x8 qf[8];
#pragma unroll
  for (int kc = 0; kc < 8; ++kc)
    qf[kc] = *reinterpret_cast<const s16x8*>(Qbh + (size_t)(qrow0 + l5) * 128 + kc * 16 + hi * 8);

  f32x16 o[4];
#pragma unroll
  for (int dt = 0; dt < 4; ++dt)
#pragma unroll
    for (int i = 0; i < 16; ++i) o[dt][i] = 0.f;
  float mrun = -3e38f, lrun = 0.f;

  auto stageK = [&](int buf, int kv0) {
    char* base = lds + buf * 16384;
#pragma unroll
    for (int i = 0; i < 4; ++i) {
      int p = (w * 4 + i) * 1024 + lane * 16;
      int row = p >> 8;
      int colb = (p & 255) ^ ((row & 7) << 4);
      gld16(Kbh + (size_t)(kv0 + row) * 128 + (colb >> 1), base + (w * 4 + i) * 1024);
    }
  };
  s16x8 vreg[4];
  auto loadV = [&](int kv0) {  // linear global -> regs
#pragma unroll
    for (int i = 0; i < 4; ++i) {
      int p = (w * 4 + i) * 1024 + lane * 16;
      int vrow = p >> 7, vcol = p & 127;
      vreg[i] = *reinterpret_cast<const s16x8*>(Vbh + (size_t)vrow * 4096 + kv0 + (vcol >> 1));
    }
  };
  auto writeV = [&]() {        // regs -> swizzled LDS
#pragma unroll
    for (int i = 0; i < 4; ++i) {
      int p = (w * 4 + i) * 1024 + lane * 16;
      int vrow = p >> 7;
      int phys = p ^ ((vrow & 7) << 4);
      *reinterpret_cast<s16x8*>(lds + 32768 + phys) = vreg[i];
    }
  };

  // prologue: K(0) -> LDS, V(0) -> regs -> LDS
  stageK(0, 0);
  loadV(0);
  asm volatile("s_waitcnt vmcnt(0)" ::: "memory");
  writeV();

  for (int t = 0; t < ntiles; ++t) {
    const int kv0 = t * 64;
    const int cur = t & 1;
    if (t + 1 < ntiles) {
      loadV(kv0 + 64);                 // V(t+1) -> regs (lands during this iter)
      stageK(cur ^ 1, kv0 + 64);       // K(t+1) -> LDS  (lands during this iter)
      asm volatile("s_waitcnt vmcnt(8) lgkmcnt(0)\n\ts_barrier" ::: "memory");  // K(t) ready; V(t) writes visible
    } else {
      asm volatile("s_waitcnt vmcnt(0) lgkmcnt(0)\n\ts_barrier" ::: "memory");
    }
    const char* Kl = lds + cur * 16384;
    const char* Vl = lds + 32768;
    if (kv0 <= qpmin + 31) {
      // ---- S^T = K * Q^T ----
      f32x16 s0, s1;
#pragma unroll
      for (int i = 0; i < 16; ++i) { s0[i] = 0.f; s1[i] = 0.f; }
      __builtin_amdgcn_s_setprio(1);
#pragma unroll
      for (int kc = 0; kc < 8; ++kc) {
        {
          int row = l5;
          int lin = row * 256 + kc * 32 + hi * 16;
          s16x8 a = *reinterpret_cast<const s16x8*>(Kl + (lin ^ ((row & 7) << 4)));
          s0 = mfma32(a, qf[kc], s0);
        }
        {
          int row = 32 + l5;
          int lin = row * 256 + kc * 32 + hi * 16;
          s16x8 a = *reinterpret_cast<const s16x8*>(Kl + (lin ^ ((row & 7) << 4)));
          s1 = mfma32(a, qf[kc], s1);
        }
      }
      __builtin_amdgcn_s_setprio(0);
      // ---- causal mask (diagonal tiles only) ----
      if (kv0 + 63 > qpmin) {
#pragma unroll
        for (int i = 0; i < 16; ++i) {
          int r0 = (i & 3) + 8 * (i >> 2) + 4 * hi;
          if (kv0 + r0 > qp) s0[i] = -3e38f;
          if (kv0 + 32 + r0 > qp) s1[i] = -3e38f;
        }
      }
      // ---- online softmax (defer-max THR=8) ----
      float pm = fmaxf(s0[0], s0[1]);
#pragma unroll
      for (int i = 2; i < 16; i += 2) pm = fmaxf(fmaxf(pm, s0[i]), s0[i + 1]);
#pragma unroll
      for (int i = 0; i < 16; i += 2) pm = fmaxf(fmaxf(pm, s1[i]), s1[i + 1]);
      {
        u32x2v rr = pswap(__float_as_uint(pm), __float_as_uint(pm));
        pm = fmaxf(pm, __uint_as_float(hi ? rr[0] : rr[1]));
      }
      float mnew = (pm > mrun + 8.f) ? pm : mrun;
      float fsc = exp2f((mrun - mnew) * CEXP);
      mrun = mnew;
      float r0 = 0.f, r1 = 0.f, r2 = 0.f, r3 = 0.f;
#pragma unroll
      for (int i = 0; i < 16; i += 4) {
        float p0 = exp2f((s0[i] - mnew) * CEXP);
        float p1 = exp2f((s0[i + 1] - mnew) * CEXP);
        float p2 = exp2f((s0[i + 2] - mnew) * CEXP);
        float p3 = exp2f((s0[i + 3] - mnew) * CEXP);
        s0[i] = p0; s0[i + 1] = p1; s0[i + 2] = p2; s0[i + 3] = p3;
        r0 += p0; r1 += p1; r2 += p2; r3 += p3;
      }
#pragma unroll
      for (int i = 0; i < 16; i += 4) {
        float p0 = exp2f((s1[i] - mnew) * CEXP);
        float p1 = exp2f((s1[i + 1] - mnew) * CEXP);
        float p2 = exp2f((s1[i + 2] - mnew) * CEXP);
        float p3 = exp2f((s1[i + 3] - mnew) * CEXP);
        s1[i] = p0; s1[i + 1] = p1; s1[i + 2] = p2; s1[i + 3] = p3;
        r0 += p0; r1 += p1; r2 += p2; r3 += p3;
      }
      float rs = (r0 + r1) + (r2 + r3);
      {
        u32x2v rr = pswap(__float_as_uint(rs), __float_as_uint(rs));
        rs += __uint_as_float(hi ? rr[0] : rr[1]);
      }
      lrun = lrun * fsc + rs;
      if (!__all(fsc == 1.f)) {
#pragma unroll
        for (int dt = 0; dt < 4; ++dt)
#pragma unroll
          for (int i = 0; i < 16; ++i) o[dt][i] *= fsc;
      }
      // ---- pack P -> PV B-fragments ----
      s16x8 pb[4];
#pragma unroll
      for (int c2 = 0; c2 < 4; ++c2) {
        const f32x16& sv = (c2 & 2) ? s1 : s0;
        const int b0 = (c2 & 1) * 8;
        unsigned x0 = cvtpk(sv[b0 + 0], sv[b0 + 1]);
        unsigned x1 = cvtpk(sv[b0 + 2], sv[b0 + 3]);
        unsigned y0 = cvtpk(sv[b0 + 4], sv[b0 + 5]);
        unsigned y1 = cvtpk(sv[b0 + 6], sv[b0 + 7]);
        u32x2v q0 = pswap(x0, y0);
        u32x2v q1 = pswap(x1, y1);
        union { unsigned u[4]; s16x8 v; } pu;
        pu.u[0] = q0[0]; pu.u[1] = q1[0]; pu.u[2] = q0[1]; pu.u[3] = q1[1];
        pb[c2] = pu.v;
      }
      // ---- O^T += V^T * P^T ----
      __builtin_amdgcn_s_setprio(1);
#pragma unroll
      for (int dt = 0; dt < 4; ++dt) {
#pragma unroll
        for (int c2 = 0; c2 < 4; ++c2) {
          int row = dt * 32 + l5;
          int lin = row * 128 + c2 * 32 + hi * 16;
          s16x8 va = *reinterpret_cast<const s16x8*>(Vl + (lin ^ ((row & 7) << 4)));
          o[dt] = mfma32(va, pb[c2], o[dt]);
        }
      }
      __builtin_amdgcn_s_setprio(0);
    }
    asm volatile("s_waitcnt lgkmcnt(0)\n\ts_barrier" ::: "memory");  // all K/V LDS reads done
    if (t + 1 < ntiles) writeV();   // V(t+1) regs -> LDS (compiler waits vmcnt(4): K(t+1) stays in flight)
  }

  // ---- epilogue: scale by 1/l, LDS transpose, coalesced store ----
  float li = 1.f / lrun;
#pragma unroll
  for (int dt = 0; dt < 4; ++dt)
#pragma unroll
    for (int i = 0; i < 16; ++i) o[dt][i] *= li;
  const int qb = w * 32 + l5;
#pragma unroll
  for (int dt = 0; dt < 4; ++dt) {
#pragma unroll
    for (int rg = 0; rg < 4; ++rg) {
      int d0 = dt * 32 + rg * 8 + hi * 4;
      unsigned w0 = cvtpk(o[dt][rg * 4 + 0], o[dt][rg * 4 + 1]);
      unsigned w1 = cvtpk(o[dt][rg * 4 + 2], o[dt][rg * 4 + 3]);
      int lin = qb * 256 + d0 * 2;
      int phys = lin ^ ((qb & 7) << 4);
      *reinterpret_cast<uint2*>(lds + phys) = make_uint2(w0, w1);
    }
  }
  __syncthreads();
  const int qr = tid >> 4, c16 = tid & 15;
#pragma unroll
  for (int it = 0; it < 8; ++it) {
    int q = qr + it * 16;
    int phys = (q * 256 + c16 * 16) ^ ((q & 7) << 4);
    s16x8 v = *reinterpret_cast<const s16x8*>(lds + phys);
    *reinterpret_cast<s16x8*>(Ao + ((size_t)(b * 2048 + qbk * 128 + q)) * 2048 + h * 128 + c16 * 8) = v;
  }
}

extern "C" void kernel_launch(void* const* d_in, const int* in_sizes, int n_in,
                              void* d_out, int out_size, void* d_ws, size_t ws_size,
                              hipStream_t stream) {
  const float* x      = (const float*)d_in[0];
  const float* past_k = (const float*)d_in[1];
  const float* past_v = (const float*)d_in[2];
  const float* Wq = (const float*)d_in[3];
  const float* bq = (const float*)d_in[4];
  const float* Wk = (const float*)d_in[5];
  const float* bk = (const float*)d_in[6];
  const float* Wv = (const float*)d_in[7];
  const float* bv = (const float*)d_in[8];
  const float* Wo = (const float*)d_in[9];
  const float* bo = (const float*)d_in[10];
  float* out = (float*)d_out;

  char* ws = (char*)d_ws;
  u16* xb   = (u16*)(ws);                    // x bf16 [4096,2048]; reused as ao after qkv
  u16* wqb  = (u16*)(ws + 16777216);
  u16* wkb  = (u16*)(ws + 25165824);
  u16* wvb  = (u16*)(ws + 33554432);
  u16* wob  = (u16*)(ws + 41943040);
  u16* kc   = (u16*)(ws + 50331648);         // K cache [B,H,4096,128]
  u16* qbuf = (u16*)(ws + 83886080);         // Q [B,H,2048,128]
  u16* vn   = (u16*)(ws + 100663296);        // V new [B,H,2048,128]
  u16* vt   = (u16*)(ws + 117440512);        // V^T [B,H,128,4096]
  u16* ao   = xb;

  cvt_kernel<<<1024, 256, 0, stream>>>(x, xb, 2097152, 30);
  cvt_kernel<<<1024, 256, 0, stream>>>(Wq, wqb, 1048576, 30);
  cvt_kernel<<<1024, 256, 0, stream>>>(Wk, wkb, 1048576, 30);
  cvt_kernel<<<1024, 256, 0, stream>>>(Wv, wvb, 1048576, 30);
  cvt_kernel<<<1024, 256, 0, stream>>>(Wo, wob, 1048576, 30);
  cvt_kernel<<<1024, 256, 0, stream>>>(past_k, kc, 2097152, 18);
  transpose_past_v<<<dim3(32, 32), 256, 0, stream>>>(past_v, vt);
  qkv_gemm<<<dim3(32, 48), 256, 0, stream>>>(xb, wqb, wkb, wvb, bq, bk, bv, qbuf, kc, vn);
  transpose_new_v<<<dim3(32, 32), 256, 0, stream>>>(vn, vt);
  attn_kernel<<<dim3(32, 16), 256, 0, stream>>>(qbuf, kc, vt, ao);
  proj_gemm<<<dim3(32, 16), 256, 0, stream>>>(ao, wob, bo, out);
}

// Round 6
// 385.022 us; speedup vs baseline: 1.9246x; 1.9246x over previous
//
#include <hip/hip_runtime.h>

typedef unsigned short u16;
typedef __attribute__((ext_vector_type(4))) float f32x4;
typedef __attribute__((ext_vector_type(16))) float f32x16;
typedef __attribute__((ext_vector_type(8))) short s16x8;
typedef __attribute__((ext_vector_type(2))) unsigned int u32x2v;

#define CEXP 0.12751742929f  // log2(e)/sqrt(128)

static __device__ __forceinline__ u16 f2bf(float x) {
  unsigned u = __float_as_uint(x);
  u = u + 0x7fffu + ((u >> 16) & 1u);
  return (u16)(u >> 16);
}
static __device__ __forceinline__ unsigned cvtpk(float a, float b) {
  unsigned r;
  asm("v_cvt_pk_bf16_f32 %0, %1, %2" : "=v"(r) : "v"(a), "v"(b));
  return r;
}
static __device__ __forceinline__ u32x2v pswap(unsigned a, unsigned b) {
  return __builtin_amdgcn_permlane32_swap(a, b, false, false);
}
static __device__ __forceinline__ f32x4 fzero() { f32x4 z; z[0]=0.f; z[1]=0.f; z[2]=0.f; z[3]=0.f; return z; }
static __device__ __forceinline__ f32x4 mfma16(s16x8 a, s16x8 b, f32x4 c) {
  return __builtin_amdgcn_mfma_f32_16x16x32_bf16(a, b, c, 0, 0, 0);
}
static __device__ __forceinline__ f32x16 mfma32(s16x8 a, s16x8 b, f32x16 c) {
  return __builtin_amdgcn_mfma_f32_32x32x16_bf16(a, b, c, 0, 0, 0);
}
static __device__ __forceinline__ void gld16(const void* g, void* l) {
  __builtin_amdgcn_global_load_lds((const __attribute__((address_space(1))) void*)g,
                                   (__attribute__((address_space(3))) void*)l, 16, 0, 0);
}

// ---------------- fp32 -> bf16 convert, dst index = i + (i>>lg)<<lg ----------------
__global__ void cvt_kernel(const float* __restrict__ s, u16* __restrict__ d, int n4, int lg) {
  int stride = gridDim.x * blockDim.x;
  for (int i4 = blockIdx.x * blockDim.x + threadIdx.x; i4 < n4; i4 += stride) {
    int i = i4 * 4;
    float4 v = *reinterpret_cast<const float4*>(s + i);
    size_t di = (size_t)i + ((size_t)(i >> lg) << lg);
    ushort4 o;
    o.x = f2bf(v.x); o.y = f2bf(v.y); o.z = f2bf(v.z); o.w = f2bf(v.w);
    *reinterpret_cast<ushort4*>(d + di) = o;
  }
}

// ---------------- V transpose: [bh][2048][128] -> Vt [bh][128][4096] ----------------
__global__ void transpose_past_v(const float* __restrict__ src, u16* __restrict__ dst) {
  __shared__ u16 tile[64 * 138];
  int bh = blockIdx.y, pt = blockIdx.x;
  const float* s = src + ((size_t)bh * 2048 + (size_t)pt * 64) * 128;
  int t = threadIdx.x;
#pragma unroll
  for (int it = 0; it < 8; ++it) {
    int idx = it * 1024 + t * 4;
    int row = idx >> 7, col = idx & 127;
    float4 v = *reinterpret_cast<const float4*>(s + idx);
    u16* d = &tile[row * 138 + col];
    d[0] = f2bf(v.x); d[1] = f2bf(v.y); d[2] = f2bf(v.z); d[3] = f2bf(v.w);
  }
  __syncthreads();
  size_t dbase = (size_t)bh * 128 * 4096 + (size_t)pt * 64;
#pragma unroll
  for (int it = 0; it < 32; ++it) {
    int o = it * 256 + t;
    int dd = o >> 6, pos = o & 63;
    dst[dbase + (size_t)dd * 4096 + pos] = tile[pos * 138 + dd];
  }
}

__global__ void transpose_new_v(const u16* __restrict__ src, u16* __restrict__ dst) {
  __shared__ u16 tile[64 * 138];
  int bh = blockIdx.y, pt = blockIdx.x;
  const u16* s = src + ((size_t)bh * 2048 + (size_t)pt * 64) * 128;
  int t = threadIdx.x;
#pragma unroll
  for (int it = 0; it < 8; ++it) {
    int idx = it * 1024 + t * 4;
    int row = idx >> 7, col = idx & 127;
    ushort4 v = *reinterpret_cast<const ushort4*>(s + idx);
    u16* d = &tile[row * 138 + col];
    d[0] = v.x; d[1] = v.y; d[2] = v.z; d[3] = v.w;
  }
  __syncthreads();
  size_t dbase = (size_t)bh * 128 * 4096 + 2048 + (size_t)pt * 64;
#pragma unroll
  for (int it = 0; it < 32; ++it) {
    int o = it * 256 + t;
    int dd = o >> 6, pos = o & 63;
    dst[dbase + (size_t)dd * 4096 + pos] = tile[pos * 138 + dd];
  }
}

// ---------------- 128x128 GEMM core, counted-vmcnt pipeline ----------------
static __device__ __forceinline__ void gemm_core(const u16* __restrict__ A, const u16* __restrict__ Wn,
                                                 int m0, char* ldsb, f32x4 (&acc)[4][4]) {
  const int tid = threadIdx.x;
  const int w = tid >> 6, lane = tid & 63, g = lane >> 4, ln = lane & 15;
#pragma unroll
  for (int mi = 0; mi < 4; ++mi)
#pragma unroll
    for (int ni = 0; ni < 4; ++ni) acc[mi][ni] = fzero();

  auto stage = [&](int buf, int k0) {
#pragma unroll
    for (int i = 0; i < 2; ++i) {
      int c = w * 2 + i;
      int p = c * 1024 + lane * 16;
      int row = p >> 6;
      int colb = (p & 63) ^ ((row & 3) << 4);
      const u16* sa = A + (size_t)(m0 + row) * 2048 + k0 + (colb >> 1);
      const u16* sw = Wn + (size_t)row * 2048 + k0 + (colb >> 1);
      char* da = ldsb + buf * 16384 + c * 1024;
      gld16(sa, da);
      gld16(sw, da + 8192);
    }
  };
  stage(0, 0);
  const int wr = w >> 1, wc = w & 1;
  for (int kt = 0; kt < 64; ++kt) {
    int cur = kt & 1;
    if (kt < 63) {
      stage(cur ^ 1, (kt + 1) * 32);
      asm volatile("s_waitcnt vmcnt(4)\n\ts_barrier" ::: "memory");  // tile kt landed; kt+1 in flight
    } else {
      asm volatile("s_waitcnt vmcnt(0)\n\ts_barrier" ::: "memory");
    }
    const char* bp = ldsb + cur * 16384;
    s16x8 af[4], bw[4];
#pragma unroll
    for (int mi = 0; mi < 4; ++mi) {
      int row = wr * 64 + mi * 16 + ln;
      int lin = row * 64 + g * 16;
      af[mi] = *reinterpret_cast<const s16x8*>(bp + (lin ^ ((row & 3) << 4)));
    }
#pragma unroll
    for (int ni = 0; ni < 4; ++ni) {
      int row = wc * 64 + ni * 16 + ln;
      int lin = row * 64 + g * 16;
      bw[ni] = *reinterpret_cast<const s16x8*>(bp + 8192 + (lin ^ ((row & 3) << 4)));
    }
#pragma unroll
    for (int mi = 0; mi < 4; ++mi)
#pragma unroll
      for (int ni = 0; ni < 4; ++ni)
        acc[mi][ni] = mfma16(af[mi], bw[ni], acc[mi][ni]);
    asm volatile("s_waitcnt lgkmcnt(0)\n\ts_barrier" ::: "memory");  // reads of cur done; no vm drain
  }
}

// ---------------- fused QKV projection ----------------
__global__ __launch_bounds__(256, 3) void qkv_gemm(const u16* __restrict__ xb,
    const u16* __restrict__ wq, const u16* __restrict__ wk, const u16* __restrict__ wv,
    const float* __restrict__ bq, const float* __restrict__ bk, const float* __restrict__ bv,
    u16* __restrict__ outq, u16* __restrict__ kc, u16* __restrict__ outv) {
  __shared__ char ldsb[32768];
  int m0 = blockIdx.x * 128;
  int ny = blockIdx.y;
  int wsel = ny >> 4, n0 = (ny & 15) * 128;
  const u16* W; const float* bias; u16* dst; int lrow, off;
  if (wsel == 0)      { W = wq; bias = bq; dst = outq; lrow = 2048; off = 0; }
  else if (wsel == 1) { W = wk; bias = bk; dst = kc;   lrow = 4096; off = 2048; }
  else                { W = wv; bias = bv; dst = outv; lrow = 2048; off = 0; }
  f32x4 acc[4][4];
  gemm_core(xb, W + (size_t)n0 * 2048, m0, ldsb, acc);
  const int tid = threadIdx.x, w = tid >> 6, lane = tid & 63, g = lane >> 4, ln = lane & 15;
  const int wr = w >> 1, wc = w & 1;
#pragma unroll
  for (int ni = 0; ni < 4; ++ni) {
    int j = n0 + wc * 64 + ni * 16 + ln;
    float bcol = bias[j];
    int h = j >> 7, hd = j & 127;
#pragma unroll
    for (int mi = 0; mi < 4; ++mi) {
#pragma unroll
      for (int r = 0; r < 4; ++r) {
        int rowg = m0 + wr * 64 + mi * 16 + g * 4 + r;
        int b = rowg >> 11, s = rowg & 2047;
        float val = acc[mi][ni][r] + bcol;
        dst[((size_t)(b * 16 + h) * lrow + off + s) * 128 + hd] = f2bf(val);
      }
    }
  }
}

// ---------------- output projection ----------------
__global__ __launch_bounds__(256, 3) void proj_gemm(const u16* __restrict__ ao, const u16* __restrict__ wo,
    const float* __restrict__ bo, float* __restrict__ out) {
  __shared__ char ldsb[32768];
  int m0 = blockIdx.x * 128, n0 = blockIdx.y * 128;
  f32x4 acc[4][4];
  gemm_core(ao, wo + (size_t)n0 * 2048, m0, ldsb, acc);
  const int tid = threadIdx.x, w = tid >> 6, lane = tid & 63, g = lane >> 4, ln = lane & 15;
  const int wr = w >> 1, wc = w & 1;
#pragma unroll
  for (int ni = 0; ni < 4; ++ni) {
    int j = n0 + wc * 64 + ni * 16 + ln;
    float bcol = bo[j];
#pragma unroll
    for (int mi = 0; mi < 4; ++mi) {
#pragma unroll
      for (int r = 0; r < 4; ++r) {
        int rowg = m0 + wr * 64 + mi * 16 + g * 4 + r;
        out[(size_t)rowg * 2048 + j] = acc[mi][ni][r] + bcol;
      }
    }
  }
}

// ---------------- flash attention (R3 structure: 32x32 MFMA, K+V LDS dbuf, vmcnt(8)) ----------------
// grid (32, 16): x = bh (XCD locality), y -> qbk remapped for complementary pairing.
__global__ __launch_bounds__(256, 2) void attn_kernel(const u16* __restrict__ Qb,
    const u16* __restrict__ Kc, const u16* __restrict__ Vt, u16* __restrict__ Ao) {
  __shared__ char lds[65536];  // 2 bufs x (K 16KB + Vt 16KB)
  const int tid = threadIdx.x, w = tid >> 6, lane = tid & 63;
  const int hi = lane >> 5, l5 = lane & 31;
  const int bh = blockIdx.x;
  const int qy = blockIdx.y;
  const int qbk = (qy & 8) ? (15 - (qy & 7)) : qy;   // complementary pairing
  const int b = bh >> 4, h = bh & 15;
  const u16* Qbh = Qb + (size_t)bh * 2048 * 128;
  const u16* Kbh = Kc + (size_t)bh * 4096 * 128;
  const u16* Vbh = Vt + (size_t)bh * 128 * 4096;

  const int qrow0 = qbk * 128 + w * 32;
  const int qp = 2048 + qrow0 + l5;
  const int qpmin = 2048 + qrow0;
  const int ntiles = (2048 + qbk * 128 + 128) >> 6;

  s16x8 qf[8];
#pragma unroll
  for (int kc = 0; kc < 8; ++kc)
    qf[kc] = *reinterpret_cast<const s16x8*>(Qbh + (size_t)(qrow0 + l5) * 128 + kc * 16 + hi * 8);

  f32x16 o[4];
#pragma unroll
  for (int dt = 0; dt < 4; ++dt)
#pragma unroll
    for (int i = 0; i < 16; ++i) o[dt][i] = 0.f;
  float mrun = -3e38f, lrun = 0.f;

  auto stage = [&](int buf, int kv0) {
    char* base = lds + buf * 32768;
#pragma unroll
    for (int i = 0; i < 4; ++i) {
      int p = (w * 4 + i) * 1024 + lane * 16;
      int row = p >> 8;
      int colb = (p & 255) ^ ((row & 7) << 4);
      gld16(Kbh + (size_t)(kv0 + row) * 128 + (colb >> 1), base + (w * 4 + i) * 1024);
      int vrow = p >> 7;
      int vcol = (p & 127) ^ ((vrow & 7) << 4);
      gld16(Vbh + (size_t)vrow * 4096 + kv0 + (vcol >> 1), base + 16384 + (w * 4 + i) * 1024);
    }
  };

  stage(0, 0);
  for (int t = 0; t < ntiles; ++t) {
    const int kv0 = t * 64;
    const int cur = t & 1;
    if (t + 1 < ntiles) {
      stage(cur ^ 1, kv0 + 64);
      asm volatile("s_waitcnt vmcnt(8)\n\ts_barrier" ::: "memory");  // tile t landed; t+1 in flight
    } else {
      asm volatile("s_waitcnt vmcnt(0)\n\ts_barrier" ::: "memory");
    }
    const char* Kl = lds + cur * 32768;
    const char* Vl = Kl + 16384;
    if (kv0 <= qpmin + 31) {
      // ---- S^T = K * Q^T : lane holds S^T[kv=(i&3)+8*(i>>2)+4hi (+32*kvt)][q=l5] ----
      f32x16 s0, s1;
#pragma unroll
      for (int i = 0; i < 16; ++i) { s0[i] = 0.f; s1[i] = 0.f; }
      __builtin_amdgcn_s_setprio(1);
#pragma unroll
      for (int kc = 0; kc < 8; ++kc) {
        {
          int row = l5;
          int lin = row * 256 + kc * 32 + hi * 16;
          s16x8 a = *reinterpret_cast<const s16x8*>(Kl + (lin ^ ((row & 7) << 4)));
          s0 = mfma32(a, qf[kc], s0);
        }
        {
          int row = 32 + l5;
          int lin = row * 256 + kc * 32 + hi * 16;
          s16x8 a = *reinterpret_cast<const s16x8*>(Kl + (lin ^ ((row & 7) << 4)));
          s1 = mfma32(a, qf[kc], s1);
        }
      }
      __builtin_amdgcn_s_setprio(0);
      // ---- causal mask (diagonal tiles only) ----
      if (kv0 + 63 > qpmin) {
#pragma unroll
        for (int i = 0; i < 16; ++i) {
          int r0 = (i & 3) + 8 * (i >> 2) + 4 * hi;
          if (kv0 + r0 > qp) s0[i] = -3e38f;
          if (kv0 + 32 + r0 > qp) s1[i] = -3e38f;
        }
      }
      // ---- online softmax (defer-max THR=8), v_max3-friendly reduce ----
      float pm = fmaxf(s0[0], s0[1]);
#pragma unroll
      for (int i = 2; i < 16; i += 2) pm = fmaxf(fmaxf(pm, s0[i]), s0[i + 1]);
#pragma unroll
      for (int i = 0; i < 16; i += 2) pm = fmaxf(fmaxf(pm, s1[i]), s1[i + 1]);
      {
        u32x2v rr = pswap(__float_as_uint(pm), __float_as_uint(pm));
        pm = fmaxf(pm, __uint_as_float(hi ? rr[0] : rr[1]));
      }
      float mnew = (pm > mrun + 8.f) ? pm : mrun;
      float fsc = exp2f((mrun - mnew) * CEXP);
      mrun = mnew;
      float r0 = 0.f, r1 = 0.f, r2 = 0.f, r3 = 0.f;
#pragma unroll
      for (int i = 0; i < 16; i += 4) {
        float p0 = exp2f((s0[i] - mnew) * CEXP);
        float p1 = exp2f((s0[i + 1] - mnew) * CEXP);
        float p2 = exp2f((s0[i + 2] - mnew) * CEXP);
        float p3 = exp2f((s0[i + 3] - mnew) * CEXP);
        s0[i] = p0; s0[i + 1] = p1; s0[i + 2] = p2; s0[i + 3] = p3;
        r0 += p0; r1 += p1; r2 += p2; r3 += p3;
      }
#pragma unroll
      for (int i = 0; i < 16; i += 4) {
        float p0 = exp2f((s1[i] - mnew) * CEXP);
        float p1 = exp2f((s1[i + 1] - mnew) * CEXP);
        float p2 = exp2f((s1[i + 2] - mnew) * CEXP);
        float p3 = exp2f((s1[i + 3] - mnew) * CEXP);
        s1[i] = p0; s1[i + 1] = p1; s1[i + 2] = p2; s1[i + 3] = p3;
        r0 += p0; r1 += p1; r2 += p2; r3 += p3;
      }
      float rs = (r0 + r1) + (r2 + r3);
      {
        u32x2v rr = pswap(__float_as_uint(rs), __float_as_uint(rs));
        rs += __uint_as_float(hi ? rr[0] : rr[1]);
      }
      lrun = lrun * fsc + rs;
      if (!__all(fsc == 1.f)) {
#pragma unroll
        for (int dt = 0; dt < 4; ++dt)
#pragma unroll
          for (int i = 0; i < 16; ++i) o[dt][i] *= fsc;
      }
      // ---- pack P -> PV B-fragments: 16 cvt_pk + 8 permlane32_swap ----
      s16x8 pb[4];
#pragma unroll
      for (int c2 = 0; c2 < 4; ++c2) {
        const f32x16& sv = (c2 & 2) ? s1 : s0;
        const int b0 = (c2 & 1) * 8;
        unsigned x0 = cvtpk(sv[b0 + 0], sv[b0 + 1]);
        unsigned x1 = cvtpk(sv[b0 + 2], sv[b0 + 3]);
        unsigned y0 = cvtpk(sv[b0 + 4], sv[b0 + 5]);
        unsigned y1 = cvtpk(sv[b0 + 6], sv[b0 + 7]);
        u32x2v q0 = pswap(x0, y0);
        u32x2v q1 = pswap(x1, y1);
        union { unsigned u[4]; s16x8 v; } pu;
        pu.u[0] = q0[0]; pu.u[1] = q1[0]; pu.u[2] = q0[1]; pu.u[3] = q1[1];
        pb[c2] = pu.v;
      }
      // ---- O^T += V^T * P^T ----
      __builtin_amdgcn_s_setprio(1);
#pragma unroll
      for (int dt = 0; dt < 4; ++dt) {
#pragma unroll
        for (int c2 = 0; c2 < 4; ++c2) {
          int row = dt * 32 + l5;
          int lin = row * 128 + c2 * 32 + hi * 16;
          s16x8 va = *reinterpret_cast<const s16x8*>(Vl + (lin ^ ((row & 7) << 4)));
          o[dt] = mfma32(va, pb[c2], o[dt]);
        }
      }
      __builtin_amdgcn_s_setprio(0);
    }
    asm volatile("s_waitcnt lgkmcnt(0)\n\ts_barrier" ::: "memory");  // reads done; no vmcnt drain
  }

  // ---- epilogue: scale by 1/l, LDS transpose, coalesced store ----
  float li = 1.f / lrun;
#pragma unroll
  for (int dt = 0; dt < 4; ++dt)
#pragma unroll
    for (int i = 0; i < 16; ++i) o[dt][i] *= li;
  const int qb = w * 32 + l5;
#pragma unroll
  for (int dt = 0; dt < 4; ++dt) {
#pragma unroll
    for (int rg = 0; rg < 4; ++rg) {
      int d0 = dt * 32 + rg * 8 + hi * 4;
      unsigned w0 = cvtpk(o[dt][rg * 4 + 0], o[dt][rg * 4 + 1]);
      unsigned w1 = cvtpk(o[dt][rg * 4 + 2], o[dt][rg * 4 + 3]);
      int lin = qb * 256 + d0 * 2;
      int phys = lin ^ ((qb & 7) << 4);
      *reinterpret_cast<uint2*>(lds + phys) = make_uint2(w0, w1);
    }
  }
  __syncthreads();
  const int qr = tid >> 4, c16 = tid & 15;
#pragma unroll
  for (int it = 0; it < 8; ++it) {
    int q = qr + it * 16;
    int phys = (q * 256 + c16 * 16) ^ ((q & 7) << 4);
    s16x8 v = *reinterpret_cast<const s16x8*>(lds + phys);
    *reinterpret_cast<s16x8*>(Ao + ((size_t)(b * 2048 + qbk * 128 + q)) * 2048 + h * 128 + c16 * 8) = v;
  }
}

extern "C" void kernel_launch(void* const* d_in, const int* in_sizes, int n_in,
                              void* d_out, int out_size, void* d_ws, size_t ws_size,
                              hipStream_t stream) {
  const float* x      = (const float*)d_in[0];
  const float* past_k = (const float*)d_in[1];
  const float* past_v = (const float*)d_in[2];
  const float* Wq = (const float*)d_in[3];
  const float* bq = (const float*)d_in[4];
  const float* Wk = (const float*)d_in[5];
  const float* bk = (const float*)d_in[6];
  const float* Wv = (const float*)d_in[7];
  const float* bv = (const float*)d_in[8];
  const float* Wo = (const float*)d_in[9];
  const float* bo = (const float*)d_in[10];
  float* out = (float*)d_out;

  char* ws = (char*)d_ws;
  u16* xb   = (u16*)(ws);                    // x bf16 [4096,2048]; reused as ao after qkv
  u16* wqb  = (u16*)(ws + 16777216);
  u16* wkb  = (u16*)(ws + 25165824);
  u16* wvb  = (u16*)(ws + 33554432);
  u16* wob  = (u16*)(ws + 41943040);
  u16* kc   = (u16*)(ws + 50331648);         // K cache [B,H,4096,128]
  u16* qbuf = (u16*)(ws + 83886080);         // Q [B,H,2048,128]
  u16* vn   = (u16*)(ws + 100663296);        // V new [B,H,2048,128]
  u16* vt   = (u16*)(ws + 117440512);        // V^T [B,H,128,4096]
  u16* ao   = xb;

  cvt_kernel<<<1024, 256, 0, stream>>>(x, xb, 2097152, 30);
  cvt_kernel<<<1024, 256, 0, stream>>>(Wq, wqb, 1048576, 30);
  cvt_kernel<<<1024, 256, 0, stream>>>(Wk, wkb, 1048576, 30);
  cvt_kernel<<<1024, 256, 0, stream>>>(Wv, wvb, 1048576, 30);
  cvt_kernel<<<1024, 256, 0, stream>>>(Wo, wob, 1048576, 30);
  cvt_kernel<<<1024, 256, 0, stream>>>(past_k, kc, 2097152, 18);
  transpose_past_v<<<dim3(32, 32), 256, 0, stream>>>(past_v, vt);
  qkv_gemm<<<dim3(32, 48), 256, 0, stream>>>(xb, wqb, wkb, wvb, bq, bk, bv, qbuf, kc, vn);
  transpose_new_v<<<dim3(32, 32), 256, 0, stream>>>(vn, vt);
  attn_kernel<<<dim3(32, 16), 256, 0, stream>>>(qbuf, kc, vt, ao);
  proj_gemm<<<dim3(32, 16), 256, 0, stream>>>(ao, wob, bo, out);
}

// Round 7
// 377.326 us; speedup vs baseline: 1.9639x; 1.0204x over previous
//
#include <hip/hip_runtime.h>

typedef unsigned short u16;
typedef __attribute__((ext_vector_type(4))) float f32x4;
typedef __attribute__((ext_vector_type(16))) float f32x16;
typedef __attribute__((ext_vector_type(8))) short s16x8;
typedef __attribute__((ext_vector_type(2))) unsigned int u32x2v;

#define CEXP 0.12751742929f  // log2(e)/sqrt(128)

static __device__ __forceinline__ u16 f2bf(float x) {
  unsigned u = __float_as_uint(x);
  u = u + 0x7fffu + ((u >> 16) & 1u);
  return (u16)(u >> 16);
}
static __device__ __forceinline__ unsigned cvtpk(float a, float b) {
  unsigned r;
  asm("v_cvt_pk_bf16_f32 %0, %1, %2" : "=v"(r) : "v"(a), "v"(b));
  return r;
}
static __device__ __forceinline__ u32x2v pswap(unsigned a, unsigned b) {
  return __builtin_amdgcn_permlane32_swap(a, b, false, false);
}
static __device__ __forceinline__ f32x4 fzero() { f32x4 z; z[0]=0.f; z[1]=0.f; z[2]=0.f; z[3]=0.f; return z; }
static __device__ __forceinline__ f32x4 mfma16(s16x8 a, s16x8 b, f32x4 c) {
  return __builtin_amdgcn_mfma_f32_16x16x32_bf16(a, b, c, 0, 0, 0);
}
static __device__ __forceinline__ f32x16 mfma32(s16x8 a, s16x8 b, f32x16 c) {
  return __builtin_amdgcn_mfma_f32_32x32x16_bf16(a, b, c, 0, 0, 0);
}
static __device__ __forceinline__ void gld16(const void* g, void* l) {
  __builtin_amdgcn_global_load_lds((const __attribute__((address_space(1))) void*)g,
                                   (__attribute__((address_space(3))) void*)l, 16, 0, 0);
}

// ---------------- fused fp32 -> bf16 conversions (x, 4 weights, past_k) ----------------
__global__ void cvt_all(const float* __restrict__ x, const float* __restrict__ wq,
                        const float* __restrict__ wk, const float* __restrict__ wv,
                        const float* __restrict__ wo, const float* __restrict__ pk,
                        u16* __restrict__ xb, u16* __restrict__ wqb, u16* __restrict__ wkb,
                        u16* __restrict__ wvb, u16* __restrict__ wob, u16* __restrict__ kc) {
  int stride = gridDim.x * blockDim.x;
  for (int i4 = blockIdx.x * blockDim.x + threadIdx.x; i4 < 8388608; i4 += stride) {
    const float* s; u16* d; int i; size_t di;
    if (i4 < 2097152)      { i = i4 * 4;             s = x;  d = xb;  di = i; }
    else if (i4 < 3145728) { i = (i4 - 2097152) * 4; s = wq; d = wqb; di = i; }
    else if (i4 < 4194304) { i = (i4 - 3145728) * 4; s = wk; d = wkb; di = i; }
    else if (i4 < 5242880) { i = (i4 - 4194304) * 4; s = wv; d = wvb; di = i; }
    else if (i4 < 6291456) { i = (i4 - 5242880) * 4; s = wo; d = wob; di = i; }
    else { i = (i4 - 6291456) * 4; s = pk; d = kc; di = (size_t)i + ((size_t)(i >> 18) << 18); }
    float4 v = *reinterpret_cast<const float4*>(s + i);
    ushort4 o;
    o.x = f2bf(v.x); o.y = f2bf(v.y); o.z = f2bf(v.z); o.w = f2bf(v.w);
    *reinterpret_cast<ushort4*>(d + di) = o;
  }
}

// ---------------- V transpose: [bh][2048][128] -> Vt [bh][128][4096] ----------------
__global__ void transpose_past_v(const float* __restrict__ src, u16* __restrict__ dst) {
  __shared__ u16 tile[64 * 138];
  int bh = blockIdx.y, pt = blockIdx.x;
  const float* s = src + ((size_t)bh * 2048 + (size_t)pt * 64) * 128;
  int t = threadIdx.x;
#pragma unroll
  for (int it = 0; it < 8; ++it) {
    int idx = it * 1024 + t * 4;
    int row = idx >> 7, col = idx & 127;
    float4 v = *reinterpret_cast<const float4*>(s + idx);
    u16* d = &tile[row * 138 + col];
    d[0] = f2bf(v.x); d[1] = f2bf(v.y); d[2] = f2bf(v.z); d[3] = f2bf(v.w);
  }
  __syncthreads();
  size_t dbase = (size_t)bh * 128 * 4096 + (size_t)pt * 64;
#pragma unroll
  for (int it = 0; it < 32; ++it) {
    int o = it * 256 + t;
    int dd = o >> 6, pos = o & 63;
    dst[dbase + (size_t)dd * 4096 + pos] = tile[pos * 138 + dd];
  }
}

__global__ void transpose_new_v(const u16* __restrict__ src, u16* __restrict__ dst) {
  __shared__ u16 tile[64 * 138];
  int bh = blockIdx.y, pt = blockIdx.x;
  const u16* s = src + ((size_t)bh * 2048 + (size_t)pt * 64) * 128;
  int t = threadIdx.x;
#pragma unroll
  for (int it = 0; it < 8; ++it) {
    int idx = it * 1024 + t * 4;
    int row = idx >> 7, col = idx & 127;
    ushort4 v = *reinterpret_cast<const ushort4*>(s + idx);
    u16* d = &tile[row * 138 + col];
    d[0] = v.x; d[1] = v.y; d[2] = v.z; d[3] = v.w;
  }
  __syncthreads();
  size_t dbase = (size_t)bh * 128 * 4096 + 2048 + (size_t)pt * 64;
#pragma unroll
  for (int it = 0; it < 32; ++it) {
    int o = it * 256 + t;
    int dd = o >> 6, pos = o & 63;
    dst[dbase + (size_t)dd * 4096 + pos] = tile[pos * 138 + dd];
  }
}

// ---------------- 128x128 GEMM core, counted-vmcnt pipeline ----------------
static __device__ __forceinline__ void gemm_core(const u16* __restrict__ A, const u16* __restrict__ Wn,
                                                 int m0, char* ldsb, f32x4 (&acc)[4][4]) {
  const int tid = threadIdx.x;
  const int w = tid >> 6, lane = tid & 63, g = lane >> 4, ln = lane & 15;
#pragma unroll
  for (int mi = 0; mi < 4; ++mi)
#pragma unroll
    for (int ni = 0; ni < 4; ++ni) acc[mi][ni] = fzero();

  auto stage = [&](int buf, int k0) {
#pragma unroll
    for (int i = 0; i < 2; ++i) {
      int c = w * 2 + i;
      int p = c * 1024 + lane * 16;
      int row = p >> 6;
      int colb = (p & 63) ^ ((row & 3) << 4);
      const u16* sa = A + (size_t)(m0 + row) * 2048 + k0 + (colb >> 1);
      const u16* sw = Wn + (size_t)row * 2048 + k0 + (colb >> 1);
      char* da = ldsb + buf * 16384 + c * 1024;
      gld16(sa, da);
      gld16(sw, da + 8192);
    }
  };
  stage(0, 0);
  const int wr = w >> 1, wc = w & 1;
  for (int kt = 0; kt < 64; ++kt) {
    int cur = kt & 1;
    if (kt < 63) {
      stage(cur ^ 1, (kt + 1) * 32);
      asm volatile("s_waitcnt vmcnt(4)\n\ts_barrier" ::: "memory");  // tile kt landed; kt+1 in flight
    } else {
      asm volatile("s_waitcnt vmcnt(0)\n\ts_barrier" ::: "memory");
    }
    const char* bp = ldsb + cur * 16384;
    s16x8 af[4], bw[4];
#pragma unroll
    for (int mi = 0; mi < 4; ++mi) {
      int row = wr * 64 + mi * 16 + ln;
      int lin = row * 64 + g * 16;
      af[mi] = *reinterpret_cast<const s16x8*>(bp + (lin ^ ((row & 3) << 4)));
    }
#pragma unroll
    for (int ni = 0; ni < 4; ++ni) {
      int row = wc * 64 + ni * 16 + ln;
      int lin = row * 64 + g * 16;
      bw[ni] = *reinterpret_cast<const s16x8*>(bp + 8192 + (lin ^ ((row & 3) << 4)));
    }
#pragma unroll
    for (int mi = 0; mi < 4; ++mi)
#pragma unroll
      for (int ni = 0; ni < 4; ++ni)
        acc[mi][ni] = mfma16(af[mi], bw[ni], acc[mi][ni]);
    asm volatile("s_waitcnt lgkmcnt(0)\n\ts_barrier" ::: "memory");  // reads of cur done; no vm drain
  }
}

// ---------------- fused QKV projection ----------------
__global__ __launch_bounds__(256, 3) void qkv_gemm(const u16* __restrict__ xb,
    const u16* __restrict__ wq, const u16* __restrict__ wk, const u16* __restrict__ wv,
    const float* __restrict__ bq, const float* __restrict__ bk, const float* __restrict__ bv,
    u16* __restrict__ outq, u16* __restrict__ kc, u16* __restrict__ outv) {
  __shared__ char ldsb[32768];
  int m0 = blockIdx.x * 128;
  int ny = blockIdx.y;
  int wsel = ny >> 4, n0 = (ny & 15) * 128;
  const u16* W; const float* bias; u16* dst; int lrow, off;
  if (wsel == 0)      { W = wq; bias = bq; dst = outq; lrow = 2048; off = 0; }
  else if (wsel == 1) { W = wk; bias = bk; dst = kc;   lrow = 4096; off = 2048; }
  else                { W = wv; bias = bv; dst = outv; lrow = 2048; off = 0; }
  f32x4 acc[4][4];
  gemm_core(xb, W + (size_t)n0 * 2048, m0, ldsb, acc);
  const int tid = threadIdx.x, w = tid >> 6, lane = tid & 63, g = lane >> 4, ln = lane & 15;
  const int wr = w >> 1, wc = w & 1;
#pragma unroll
  for (int ni = 0; ni < 4; ++ni) {
    int j = n0 + wc * 64 + ni * 16 + ln;
    float bcol = bias[j];
    int h = j >> 7, hd = j & 127;
#pragma unroll
    for (int mi = 0; mi < 4; ++mi) {
#pragma unroll
      for (int r = 0; r < 4; ++r) {
        int rowg = m0 + wr * 64 + mi * 16 + g * 4 + r;
        int b = rowg >> 11, s = rowg & 2047;
        float val = acc[mi][ni][r] + bcol;
        dst[((size_t)(b * 16 + h) * lrow + off + s) * 128 + hd] = f2bf(val);
      }
    }
  }
}

// ---------------- output projection ----------------
__global__ __launch_bounds__(256, 3) void proj_gemm(const u16* __restrict__ ao, const u16* __restrict__ wo,
    const float* __restrict__ bo, float* __restrict__ out) {
  __shared__ char ldsb[32768];
  int m0 = blockIdx.x * 128, n0 = blockIdx.y * 128;
  f32x4 acc[4][4];
  gemm_core(ao, wo + (size_t)n0 * 2048, m0, ldsb, acc);
  const int tid = threadIdx.x, w = tid >> 6, lane = tid & 63, g = lane >> 4, ln = lane & 15;
  const int wr = w >> 1, wc = w & 1;
#pragma unroll
  for (int ni = 0; ni < 4; ++ni) {
    int j = n0 + wc * 64 + ni * 16 + ln;
    float bcol = bo[j];
#pragma unroll
    for (int mi = 0; mi < 4; ++mi) {
#pragma unroll
      for (int r = 0; r < 4; ++r) {
        int rowg = m0 + wr * 64 + mi * 16 + g * 4 + r;
        out[(size_t)rowg * 2048 + j] = acc[mi][ni][r] + bcol;
      }
    }
  }
}

// ---------------- flash attention (32x32 MFMA, K+V LDS dbuf, vmcnt(8), l via MFMA) ----------------
// grid (32, 16): x = bh (XCD locality), y -> qbk remapped for complementary pairing.
__global__ __launch_bounds__(256, 2) void attn_kernel(const u16* __restrict__ Qb,
    const u16* __restrict__ Kc, const u16* __restrict__ Vt, u16* __restrict__ Ao) {
  __shared__ char lds[65536];  // 2 bufs x (K 16KB + Vt 16KB)
  const int tid = threadIdx.x, w = tid >> 6, lane = tid & 63;
  const int hi = lane >> 5, l5 = lane & 31;
  const int bh = blockIdx.x;
  const int qy = blockIdx.y;
  const int qbk = (qy & 8) ? (15 - (qy & 7)) : qy;   // complementary pairing
  const int b = bh >> 4, h = bh & 15;
  const u16* Qbh = Qb + (size_t)bh * 2048 * 128;
  const u16* Kbh = Kc + (size_t)bh * 4096 * 128;
  const u16* Vbh = Vt + (size_t)bh * 128 * 4096;

  const int qrow0 = qbk * 128 + w * 32;
  const int qp = 2048 + qrow0 + l5;
  const int qpmin = 2048 + qrow0;
  const int ntiles = (2048 + qbk * 128 + 128) >> 6;

  s16x8 qf[8];
#pragma unroll
  for (int kc = 0; kc < 8; ++kc)
    qf[kc] = *reinterpret_cast<const s16x8*>(Qbh + (size_t)(qrow0 + l5) * 128 + kc * 16 + hi * 8);

  s16x8 ones;
#pragma unroll
  for (int j = 0; j < 8; ++j) ones[j] = (short)0x3F80;  // bf16 1.0

  f32x16 o[4], o_l;
#pragma unroll
  for (int dt = 0; dt < 4; ++dt)
#pragma unroll
    for (int i = 0; i < 16; ++i) o[dt][i] = 0.f;
#pragma unroll
  for (int i = 0; i < 16; ++i) o_l[i] = 0.f;
  float mrun = -3e38f;

  auto stage = [&](int buf, int kv0) {
    char* base = lds + buf * 32768;
#pragma unroll
    for (int i = 0; i < 4; ++i) {
      int p = (w * 4 + i) * 1024 + lane * 16;
      int row = p >> 8;
      int colb = (p & 255) ^ ((row & 7) << 4);
      gld16(Kbh + (size_t)(kv0 + row) * 128 + (colb >> 1), base + (w * 4 + i) * 1024);
      int vrow = p >> 7;
      int vcol = (p & 127) ^ ((vrow & 7) << 4);
      gld16(Vbh + (size_t)vrow * 4096 + kv0 + (vcol >> 1), base + 16384 + (w * 4 + i) * 1024);
    }
  };

  stage(0, 0);
  for (int t = 0; t < ntiles; ++t) {
    const int kv0 = t * 64;
    const int cur = t & 1;
    if (t + 1 < ntiles) {
      stage(cur ^ 1, kv0 + 64);
      asm volatile("s_waitcnt vmcnt(8)\n\ts_barrier" ::: "memory");  // tile t landed; t+1 in flight
    } else {
      asm volatile("s_waitcnt vmcnt(0)\n\ts_barrier" ::: "memory");
    }
    const char* Kl = lds + cur * 32768;
    const char* Vl = Kl + 16384;
    if (kv0 <= qpmin + 31) {
      // ---- S^T = K * Q^T : lane holds S^T[kv=(i&3)+8*(i>>2)+4hi (+32*kvt)][q=l5] ----
      f32x16 s0, s1;
#pragma unroll
      for (int i = 0; i < 16; ++i) { s0[i] = 0.f; s1[i] = 0.f; }
      __builtin_amdgcn_s_setprio(1);
#pragma unroll
      for (int kc = 0; kc < 8; ++kc) {
        {
          int row = l5;
          int lin = row * 256 + kc * 32 + hi * 16;
          s16x8 a = *reinterpret_cast<const s16x8*>(Kl + (lin ^ ((row & 7) << 4)));
          s0 = mfma32(a, qf[kc], s0);
        }
        {
          int row = 32 + l5;
          int lin = row * 256 + kc * 32 + hi * 16;
          s16x8 a = *reinterpret_cast<const s16x8*>(Kl + (lin ^ ((row & 7) << 4)));
          s1 = mfma32(a, qf[kc], s1);
        }
      }
      __builtin_amdgcn_s_setprio(0);
      // ---- causal mask (diagonal tiles only) ----
      if (kv0 + 63 > qpmin) {
#pragma unroll
        for (int i = 0; i < 16; ++i) {
          int r0 = (i & 3) + 8 * (i >> 2) + 4 * hi;
          if (kv0 + r0 > qp) s0[i] = -3e38f;
          if (kv0 + 32 + r0 > qp) s1[i] = -3e38f;
        }
      }
      // ---- online softmax (defer-max THR=8); denominator comes from MFMA below ----
      float pm = fmaxf(s0[0], s0[1]);
#pragma unroll
      for (int i = 2; i < 16; i += 2) pm = fmaxf(fmaxf(pm, s0[i]), s0[i + 1]);
#pragma unroll
      for (int i = 0; i < 16; i += 2) pm = fmaxf(fmaxf(pm, s1[i]), s1[i + 1]);
      {
        u32x2v rr = pswap(__float_as_uint(pm), __float_as_uint(pm));
        pm = fmaxf(pm, __uint_as_float(hi ? rr[0] : rr[1]));
      }
      float mnew = (pm > mrun + 8.f) ? pm : mrun;
      float fsc = exp2f((mrun - mnew) * CEXP);
      mrun = mnew;
#pragma unroll
      for (int i = 0; i < 16; ++i) s0[i] = exp2f((s0[i] - mnew) * CEXP);
#pragma unroll
      for (int i = 0; i < 16; ++i) s1[i] = exp2f((s1[i] - mnew) * CEXP);
      if (!__all(fsc == 1.f)) {
#pragma unroll
        for (int dt = 0; dt < 4; ++dt)
#pragma unroll
          for (int i = 0; i < 16; ++i) o[dt][i] *= fsc;
        o_l[0] *= fsc;   // only element 0 is read; increments are element-uniform
      }
      // ---- pack P -> PV B-fragments: 16 cvt_pk + 8 permlane32_swap ----
      s16x8 pb[4];
#pragma unroll
      for (int c2 = 0; c2 < 4; ++c2) {
        const f32x16& sv = (c2 & 2) ? s1 : s0;
        const int b0 = (c2 & 1) * 8;
        unsigned x0 = cvtpk(sv[b0 + 0], sv[b0 + 1]);
        unsigned x1 = cvtpk(sv[b0 + 2], sv[b0 + 3]);
        unsigned y0 = cvtpk(sv[b0 + 4], sv[b0 + 5]);
        unsigned y1 = cvtpk(sv[b0 + 6], sv[b0 + 7]);
        u32x2v q0 = pswap(x0, y0);
        u32x2v q1 = pswap(x1, y1);
        union { unsigned u[4]; s16x8 v; } pu;
        pu.u[0] = q0[0]; pu.u[1] = q1[0]; pu.u[2] = q0[1]; pu.u[3] = q1[1];
        pb[c2] = pu.v;
      }
      // ---- O^T += V^T * P^T ; l += 1^T * P^T (denominator on the MFMA pipe) ----
      __builtin_amdgcn_s_setprio(1);
#pragma unroll
      for (int dt = 0; dt < 4; ++dt) {
#pragma unroll
        for (int c2 = 0; c2 < 4; ++c2) {
          int row = dt * 32 + l5;
          int lin = row * 128 + c2 * 32 + hi * 16;
          s16x8 va = *reinterpret_cast<const s16x8*>(Vl + (lin ^ ((row & 7) << 4)));
          o[dt] = mfma32(va, pb[c2], o[dt]);
        }
      }
#pragma unroll
      for (int c2 = 0; c2 < 4; ++c2) o_l = mfma32(ones, pb[c2], o_l);
      __builtin_amdgcn_s_setprio(0);
    }
    asm volatile("s_waitcnt lgkmcnt(0)\n\ts_barrier" ::: "memory");  // reads done; no vmcnt drain
  }

  // ---- epilogue: scale by 1/l, LDS transpose, coalesced store ----
  float li = 1.f / o_l[0];
#pragma unroll
  for (int dt = 0; dt < 4; ++dt)
#pragma unroll
    for (int i = 0; i < 16; ++i) o[dt][i] *= li;
  const int qb = w * 32 + l5;
#pragma unroll
  for (int dt = 0; dt < 4; ++dt) {
#pragma unroll
    for (int rg = 0; rg < 4; ++rg) {
      int d0 = dt * 32 + rg * 8 + hi * 4;
      unsigned w0 = cvtpk(o[dt][rg * 4 + 0], o[dt][rg * 4 + 1]);
      unsigned w1 = cvtpk(o[dt][rg * 4 + 2], o[dt][rg * 4 + 3]);
      int lin = qb * 256 + d0 * 2;
      int phys = lin ^ ((qb & 7) << 4);
      *reinterpret_cast<uint2*>(lds + phys) = make_uint2(w0, w1);
    }
  }
  __syncthreads();
  const int qr = tid >> 4, c16 = tid & 15;
#pragma unroll
  for (int it = 0; it < 8; ++it) {
    int q = qr + it * 16;
    int phys = (q * 256 + c16 * 16) ^ ((q & 7) << 4);
    s16x8 v = *reinterpret_cast<const s16x8*>(lds + phys);
    *reinterpret_cast<s16x8*>(Ao + ((size_t)(b * 2048 + qbk * 128 + q)) * 2048 + h * 128 + c16 * 8) = v;
  }
}

extern "C" void kernel_launch(void* const* d_in, const int* in_sizes, int n_in,
                              void* d_out, int out_size, void* d_ws, size_t ws_size,
                              hipStream_t stream) {
  const float* x      = (const float*)d_in[0];
  const float* past_k = (const float*)d_in[1];
  const float* past_v = (const float*)d_in[2];
  const float* Wq = (const float*)d_in[3];
  const float* bq = (const float*)d_in[4];
  const float* Wk = (const float*)d_in[5];
  const float* bk = (const float*)d_in[6];
  const float* Wv = (const float*)d_in[7];
  const float* bv = (const float*)d_in[8];
  const float* Wo = (const float*)d_in[9];
  const float* bo = (const float*)d_in[10];
  float* out = (float*)d_out;

  char* ws = (char*)d_ws;
  u16* xb   = (u16*)(ws);                    // x bf16 [4096,2048]; reused as ao after qkv
  u16* wqb  = (u16*)(ws + 16777216);
  u16* wkb  = (u16*)(ws + 25165824);
  u16* wvb  = (u16*)(ws + 33554432);
  u16* wob  = (u16*)(ws + 41943040);
  u16* kc   = (u16*)(ws + 50331648);         // K cache [B,H,4096,128]
  u16* qbuf = (u16*)(ws + 83886080);         // Q [B,H,2048,128]
  u16* vn   = (u16*)(ws + 100663296);        // V new [B,H,2048,128]
  u16* vt   = (u16*)(ws + 117440512);        // V^T [B,H,128,4096]
  u16* ao   = xb;

  cvt_all<<<2048, 256, 0, stream>>>(x, Wq, Wk, Wv, Wo, past_k, xb, wqb, wkb, wvb, wob, kc);
  transpose_past_v<<<dim3(32, 32), 256, 0, stream>>>(past_v, vt);
  qkv_gemm<<<dim3(32, 48), 256, 0, stream>>>(xb, wqb, wkb, wvb, bq, bk, bv, qbuf, kc, vn);
  transpose_new_v<<<dim3(32, 32), 256, 0, stream>>>(vn, vt);
  attn_kernel<<<dim3(32, 16), 256, 0, stream>>>(qbuf, kc, vt, ao);
  proj_gemm<<<dim3(32, 16), 256, 0, stream>>>(ao, wob, bo, out);
}

// Round 8
// 376.912 us; speedup vs baseline: 1.9661x; 1.0011x over previous
//
#include <hip/hip_runtime.h>

typedef unsigned short u16;
typedef __attribute__((ext_vector_type(4))) float f32x4;
typedef __attribute__((ext_vector_type(16))) float f32x16;
typedef __attribute__((ext_vector_type(8))) short s16x8;
typedef __attribute__((ext_vector_type(2))) unsigned int u32x2v;

#define CEXP 0.12751742929f  // log2(e)/sqrt(128)

static __device__ __forceinline__ u16 f2bf(float x) {
  unsigned u = __float_as_uint(x);
  u = u + 0x7fffu + ((u >> 16) & 1u);
  return (u16)(u >> 16);
}
static __device__ __forceinline__ unsigned cvtpk(float a, float b) {
  unsigned r;
  asm("v_cvt_pk_bf16_f32 %0, %1, %2" : "=v"(r) : "v"(a), "v"(b));
  return r;
}
static __device__ __forceinline__ u32x2v pswap(unsigned a, unsigned b) {
  return __builtin_amdgcn_permlane32_swap(a, b, false, false);
}
static __device__ __forceinline__ f32x4 fzero() { f32x4 z; z[0]=0.f; z[1]=0.f; z[2]=0.f; z[3]=0.f; return z; }
static __device__ __forceinline__ f32x4 mfma16(s16x8 a, s16x8 b, f32x4 c) {
  return __builtin_amdgcn_mfma_f32_16x16x32_bf16(a, b, c, 0, 0, 0);
}
static __device__ __forceinline__ f32x16 mfma32(s16x8 a, s16x8 b, f32x16 c) {
  return __builtin_amdgcn_mfma_f32_32x32x16_bf16(a, b, c, 0, 0, 0);
}
static __device__ __forceinline__ void gld16(const void* g, void* l) {
  __builtin_amdgcn_global_load_lds((const __attribute__((address_space(1))) void*)g,
                                   (__attribute__((address_space(3))) void*)l, 16, 0, 0);
}

// ---------------- fused fp32 -> bf16 conversions (x, 4 weights, past_k) ----------------
__global__ void cvt_all(const float* __restrict__ x, const float* __restrict__ wq,
                        const float* __restrict__ wk, const float* __restrict__ wv,
                        const float* __restrict__ wo, const float* __restrict__ pk,
                        u16* __restrict__ xb, u16* __restrict__ wqb, u16* __restrict__ wkb,
                        u16* __restrict__ wvb, u16* __restrict__ wob, u16* __restrict__ kc) {
  int stride = gridDim.x * blockDim.x;
  for (int i4 = blockIdx.x * blockDim.x + threadIdx.x; i4 < 8388608; i4 += stride) {
    const float* s; u16* d; int i; size_t di;
    if (i4 < 2097152)      { i = i4 * 4;             s = x;  d = xb;  di = i; }
    else if (i4 < 3145728) { i = (i4 - 2097152) * 4; s = wq; d = wqb; di = i; }
    else if (i4 < 4194304) { i = (i4 - 3145728) * 4; s = wk; d = wkb; di = i; }
    else if (i4 < 5242880) { i = (i4 - 4194304) * 4; s = wv; d = wvb; di = i; }
    else if (i4 < 6291456) { i = (i4 - 5242880) * 4; s = wo; d = wob; di = i; }
    else { i = (i4 - 6291456) * 4; s = pk; d = kc; di = (size_t)i + ((size_t)(i >> 18) << 18); }
    float4 v = *reinterpret_cast<const float4*>(s + i);
    ushort4 o;
    o.x = f2bf(v.x); o.y = f2bf(v.y); o.z = f2bf(v.z); o.w = f2bf(v.w);
    *reinterpret_cast<ushort4*>(d + di) = o;
  }
}

// ---------------- V transpose: [bh][2048][128] -> Vt [bh][128][4096] ----------------
__global__ void transpose_past_v(const float* __restrict__ src, u16* __restrict__ dst) {
  __shared__ u16 tile[64 * 138];
  int bh = blockIdx.y, pt = blockIdx.x;
  const float* s = src + ((size_t)bh * 2048 + (size_t)pt * 64) * 128;
  int t = threadIdx.x;
#pragma unroll
  for (int it = 0; it < 8; ++it) {
    int idx = it * 1024 + t * 4;
    int row = idx >> 7, col = idx & 127;
    float4 v = *reinterpret_cast<const float4*>(s + idx);
    u16* d = &tile[row * 138 + col];
    d[0] = f2bf(v.x); d[1] = f2bf(v.y); d[2] = f2bf(v.z); d[3] = f2bf(v.w);
  }
  __syncthreads();
  size_t dbase = (size_t)bh * 128 * 4096 + (size_t)pt * 64;
#pragma unroll
  for (int it = 0; it < 32; ++it) {
    int o = it * 256 + t;
    int dd = o >> 6, pos = o & 63;
    dst[dbase + (size_t)dd * 4096 + pos] = tile[pos * 138 + dd];
  }
}

__global__ void transpose_new_v(const u16* __restrict__ src, u16* __restrict__ dst) {
  __shared__ u16 tile[64 * 138];
  int bh = blockIdx.y, pt = blockIdx.x;
  const u16* s = src + ((size_t)bh * 2048 + (size_t)pt * 64) * 128;
  int t = threadIdx.x;
#pragma unroll
  for (int it = 0; it < 8; ++it) {
    int idx = it * 1024 + t * 4;
    int row = idx >> 7, col = idx & 127;
    ushort4 v = *reinterpret_cast<const ushort4*>(s + idx);
    u16* d = &tile[row * 138 + col];
    d[0] = v.x; d[1] = v.y; d[2] = v.z; d[3] = v.w;
  }
  __syncthreads();
  size_t dbase = (size_t)bh * 128 * 4096 + 2048 + (size_t)pt * 64;
#pragma unroll
  for (int it = 0; it < 32; ++it) {
    int o = it * 256 + t;
    int dd = o >> 6, pos = o & 63;
    dst[dbase + (size_t)dd * 4096 + pos] = tile[pos * 138 + dd];
  }
}

// ---------------- 128x128 GEMM core, counted-vmcnt pipeline ----------------
static __device__ __forceinline__ void gemm_core(const u16* __restrict__ A, const u16* __restrict__ Wn,
                                                 int m0, char* ldsb, f32x4 (&acc)[4][4]) {
  const int tid = threadIdx.x;
  const int w = tid >> 6, lane = tid & 63, g = lane >> 4, ln = lane & 15;
#pragma unroll
  for (int mi = 0; mi < 4; ++mi)
#pragma unroll
    for (int ni = 0; ni < 4; ++ni) acc[mi][ni] = fzero();

  auto stage = [&](int buf, int k0) {
#pragma unroll
    for (int i = 0; i < 2; ++i) {
      int c = w * 2 + i;
      int p = c * 1024 + lane * 16;
      int row = p >> 6;
      int colb = (p & 63) ^ ((row & 3) << 4);
      const u16* sa = A + (size_t)(m0 + row) * 2048 + k0 + (colb >> 1);
      const u16* sw = Wn + (size_t)row * 2048 + k0 + (colb >> 1);
      char* da = ldsb + buf * 16384 + c * 1024;
      gld16(sa, da);
      gld16(sw, da + 8192);
    }
  };
  stage(0, 0);
  const int wr = w >> 1, wc = w & 1;
  for (int kt = 0; kt < 64; ++kt) {
    int cur = kt & 1;
    if (kt < 63) {
      stage(cur ^ 1, (kt + 1) * 32);
      asm volatile("s_waitcnt vmcnt(4)\n\ts_barrier" ::: "memory");  // tile kt landed; kt+1 in flight
    } else {
      asm volatile("s_waitcnt vmcnt(0)\n\ts_barrier" ::: "memory");
    }
    const char* bp = ldsb + cur * 16384;
    s16x8 af[4], bw[4];
#pragma unroll
    for (int mi = 0; mi < 4; ++mi) {
      int row = wr * 64 + mi * 16 + ln;
      int lin = row * 64 + g * 16;
      af[mi] = *reinterpret_cast<const s16x8*>(bp + (lin ^ ((row & 3) << 4)));
    }
#pragma unroll
    for (int ni = 0; ni < 4; ++ni) {
      int row = wc * 64 + ni * 16 + ln;
      int lin = row * 64 + g * 16;
      bw[ni] = *reinterpret_cast<const s16x8*>(bp + 8192 + (lin ^ ((row & 3) << 4)));
    }
#pragma unroll
    for (int mi = 0; mi < 4; ++mi)
#pragma unroll
      for (int ni = 0; ni < 4; ++ni)
        acc[mi][ni] = mfma16(af[mi], bw[ni], acc[mi][ni]);
    asm volatile("s_waitcnt lgkmcnt(0)\n\ts_barrier" ::: "memory");  // reads of cur done; no vm drain
  }
}

// ---------------- fused QKV projection ----------------
__global__ __launch_bounds__(256, 3) void qkv_gemm(const u16* __restrict__ xb,
    const u16* __restrict__ wq, const u16* __restrict__ wk, const u16* __restrict__ wv,
    const float* __restrict__ bq, const float* __restrict__ bk, const float* __restrict__ bv,
    u16* __restrict__ outq, u16* __restrict__ kc, u16* __restrict__ outv) {
  __shared__ char ldsb[32768];
  int m0 = blockIdx.x * 128;
  int ny = blockIdx.y;
  int wsel = ny >> 4, n0 = (ny & 15) * 128;
  const u16* W; const float* bias; u16* dst; int lrow, off;
  if (wsel == 0)      { W = wq; bias = bq; dst = outq; lrow = 2048; off = 0; }
  else if (wsel == 1) { W = wk; bias = bk; dst = kc;   lrow = 4096; off = 2048; }
  else                { W = wv; bias = bv; dst = outv; lrow = 2048; off = 0; }
  f32x4 acc[4][4];
  gemm_core(xb, W + (size_t)n0 * 2048, m0, ldsb, acc);
  const int tid = threadIdx.x, w = tid >> 6, lane = tid & 63, g = lane >> 4, ln = lane & 15;
  const int wr = w >> 1, wc = w & 1;
#pragma unroll
  for (int ni = 0; ni < 4; ++ni) {
    int j = n0 + wc * 64 + ni * 16 + ln;
    float bcol = bias[j];
    int h = j >> 7, hd = j & 127;
#pragma unroll
    for (int mi = 0; mi < 4; ++mi) {
#pragma unroll
      for (int r = 0; r < 4; ++r) {
        int rowg = m0 + wr * 64 + mi * 16 + g * 4 + r;
        int b = rowg >> 11, s = rowg & 2047;
        float val = acc[mi][ni][r] + bcol;
        dst[((size_t)(b * 16 + h) * lrow + off + s) * 128 + hd] = f2bf(val);
      }
    }
  }
}

// ---------------- output projection ----------------
__global__ __launch_bounds__(256, 3) void proj_gemm(const u16* __restrict__ ao, const u16* __restrict__ wo,
    const float* __restrict__ bo, float* __restrict__ out) {
  __shared__ char ldsb[32768];
  int m0 = blockIdx.x * 128, n0 = blockIdx.y * 128;
  f32x4 acc[4][4];
  gemm_core(ao, wo + (size_t)n0 * 2048, m0, ldsb, acc);
  const int tid = threadIdx.x, w = tid >> 6, lane = tid & 63, g = lane >> 4, ln = lane & 15;
  const int wr = w >> 1, wc = w & 1;
#pragma unroll
  for (int ni = 0; ni < 4; ++ni) {
    int j = n0 + wc * 64 + ni * 16 + ln;
    float bcol = bo[j];
#pragma unroll
    for (int mi = 0; mi < 4; ++mi) {
#pragma unroll
      for (int r = 0; r < 4; ++r) {
        int rowg = m0 + wr * 64 + mi * 16 + g * 4 + r;
        out[(size_t)rowg * 2048 + j] = acc[mi][ni][r] + bcol;
      }
    }
  }
}

// ---------------- flash attention (32x32 MFMA, fragment-major LDS: 0 bank conflicts) ----------------
// K tile stored as 32 frags f=rh*16+kc*2+hi, each 32 lanes x 16B contiguous.
// V tile stored as 32 frags g=dt*8+c2*2+hi likewise. Reads are base+lane*16 (lane-linear).
// grid (32, 16): x = bh (XCD locality), y -> qbk remapped for complementary pairing.
__global__ __launch_bounds__(256, 2) void attn_kernel(const u16* __restrict__ Qb,
    const u16* __restrict__ Kc, const u16* __restrict__ Vt, u16* __restrict__ Ao) {
  __shared__ char lds[65536];  // 2 bufs x (K 16KB + Vt 16KB)
  const int tid = threadIdx.x, w = tid >> 6, lane = tid & 63;
  const int hi = lane >> 5, l5 = lane & 31;
  const int bh = blockIdx.x;
  const int qy = blockIdx.y;
  const int qbk = (qy & 8) ? (15 - (qy & 7)) : qy;   // complementary pairing
  const int b = bh >> 4, h = bh & 15;
  const u16* Qbh = Qb + (size_t)bh * 2048 * 128;
  const u16* Kbh = Kc + (size_t)bh * 4096 * 128;
  const u16* Vbh = Vt + (size_t)bh * 128 * 4096;

  const int qrow0 = qbk * 128 + w * 32;
  const int qp = 2048 + qrow0 + l5;
  const int qpmin = 2048 + qrow0;
  const int ntiles = (2048 + qbk * 128 + 128) >> 6;

  s16x8 qf[8];
#pragma unroll
  for (int kc = 0; kc < 8; ++kc)
    qf[kc] = *reinterpret_cast<const s16x8*>(Qbh + (size_t)(qrow0 + l5) * 128 + kc * 16 + hi * 8);

  s16x8 ones;
#pragma unroll
  for (int j = 0; j < 8; ++j) ones[j] = (short)0x3F80;  // bf16 1.0

  f32x16 o[4], o_l;
#pragma unroll
  for (int dt = 0; dt < 4; ++dt)
#pragma unroll
    for (int i = 0; i < 16; ++i) o[dt][i] = 0.f;
#pragma unroll
  for (int i = 0; i < 16; ++i) o_l[i] = 0.f;
  float mrun = -3e38f;

  // fragment-major staging: per-lane global src, lane-linear LDS dest
  auto stage = [&](int buf, int kv0) {
    char* base = lds + buf * 32768;
#pragma unroll
    for (int i = 0; i < 4; ++i) {
      int cc = w * 4 + i;                   // chunk 0..15 (1KB each)
      int f = 2 * cc + hi;                  // K frag: f = rh*16 + kc*2 + fh
      int rh = f >> 4, kcf = (f >> 1) & 7, fh = f & 1;
      gld16(Kbh + (size_t)(kv0 + rh * 32 + l5) * 128 + kcf * 16 + fh * 8,
            base + cc * 1024);
      int g2 = 2 * cc + hi;                 // V frag: g = dt*8 + c2*2 + gh
      int dt = g2 >> 3, c2 = (g2 >> 1) & 3, gh = g2 & 1;
      gld16(Vbh + (size_t)(dt * 32 + l5) * 4096 + kv0 + c2 * 16 + gh * 8,
            base + 16384 + cc * 1024);
    }
  };

  stage(0, 0);
  for (int t = 0; t < ntiles; ++t) {
    const int kv0 = t * 64;
    const int cur = t & 1;
    if (t + 1 < ntiles) {
      stage(cur ^ 1, kv0 + 64);
      asm volatile("s_waitcnt vmcnt(8)\n\ts_barrier" ::: "memory");  // tile t landed; t+1 in flight
    } else {
      asm volatile("s_waitcnt vmcnt(0)\n\ts_barrier" ::: "memory");
    }
    const char* Kl = lds + cur * 32768;
    const char* Vl = Kl + 16384;
    if (kv0 <= qpmin + 31) {
      // ---- S^T = K * Q^T : lane holds S^T[kv=(i&3)+8*(i>>2)+4hi (+32*kvt)][q=l5] ----
      f32x16 s0, s1;
#pragma unroll
      for (int i = 0; i < 16; ++i) { s0[i] = 0.f; s1[i] = 0.f; }
      __builtin_amdgcn_s_setprio(1);
#pragma unroll
      for (int kc = 0; kc < 8; ++kc) {
        s16x8 a0 = *reinterpret_cast<const s16x8*>(Kl + kc * 1024 + lane * 16);
        s16x8 a1 = *reinterpret_cast<const s16x8*>(Kl + 8192 + kc * 1024 + lane * 16);
        s0 = mfma32(a0, qf[kc], s0);
        s1 = mfma32(a1, qf[kc], s1);
      }
      __builtin_amdgcn_s_setprio(0);
      // ---- causal mask (diagonal tiles only) ----
      if (kv0 + 63 > qpmin) {
#pragma unroll
        for (int i = 0; i < 16; ++i) {
          int r0 = (i & 3) + 8 * (i >> 2) + 4 * hi;
          if (kv0 + r0 > qp) s0[i] = -3e38f;
          if (kv0 + 32 + r0 > qp) s1[i] = -3e38f;
        }
      }
      // ---- online softmax (defer-max THR=8); denominator via MFMA below ----
      float pm = fmaxf(s0[0], s0[1]);
#pragma unroll
      for (int i = 2; i < 16; i += 2) pm = fmaxf(fmaxf(pm, s0[i]), s0[i + 1]);
#pragma unroll
      for (int i = 0; i < 16; i += 2) pm = fmaxf(fmaxf(pm, s1[i]), s1[i + 1]);
      {
        u32x2v rr = pswap(__float_as_uint(pm), __float_as_uint(pm));
        pm = fmaxf(pm, __uint_as_float(hi ? rr[0] : rr[1]));
      }
      float mnew = (pm > mrun + 8.f) ? pm : mrun;
      float fsc = exp2f((mrun - mnew) * CEXP);
      mrun = mnew;
#pragma unroll
      for (int i = 0; i < 16; ++i) s0[i] = exp2f((s0[i] - mnew) * CEXP);
#pragma unroll
      for (int i = 0; i < 16; ++i) s1[i] = exp2f((s1[i] - mnew) * CEXP);
      if (!__all(fsc == 1.f)) {
#pragma unroll
        for (int dt = 0; dt < 4; ++dt)
#pragma unroll
          for (int i = 0; i < 16; ++i) o[dt][i] *= fsc;
        o_l[0] *= fsc;   // only element 0 is read; increments are element-uniform
      }
      // ---- pack P -> PV B-fragments: 16 cvt_pk + 8 permlane32_swap ----
      s16x8 pb[4];
#pragma unroll
      for (int c2 = 0; c2 < 4; ++c2) {
        const f32x16& sv = (c2 & 2) ? s1 : s0;
        const int b0 = (c2 & 1) * 8;
        unsigned x0 = cvtpk(sv[b0 + 0], sv[b0 + 1]);
        unsigned x1 = cvtpk(sv[b0 + 2], sv[b0 + 3]);
        unsigned y0 = cvtpk(sv[b0 + 4], sv[b0 + 5]);
        unsigned y1 = cvtpk(sv[b0 + 6], sv[b0 + 7]);
        u32x2v q0 = pswap(x0, y0);
        u32x2v q1 = pswap(x1, y1);
        union { unsigned u[4]; s16x8 v; } pu;
        pu.u[0] = q0[0]; pu.u[1] = q1[0]; pu.u[2] = q0[1]; pu.u[3] = q1[1];
        pb[c2] = pu.v;
      }
      // ---- O^T += V^T * P^T ; l += 1^T * P^T (denominator on the MFMA pipe) ----
      __builtin_amdgcn_s_setprio(1);
#pragma unroll
      for (int dt = 0; dt < 4; ++dt) {
#pragma unroll
        for (int c2 = 0; c2 < 4; ++c2) {
          s16x8 va = *reinterpret_cast<const s16x8*>(Vl + dt * 4096 + c2 * 1024 + lane * 16);
          o[dt] = mfma32(va, pb[c2], o[dt]);
        }
      }
#pragma unroll
      for (int c2 = 0; c2 < 4; ++c2) o_l = mfma32(ones, pb[c2], o_l);
      __builtin_amdgcn_s_setprio(0);
    }
    asm volatile("s_waitcnt lgkmcnt(0)\n\ts_barrier" ::: "memory");  // reads done; no vmcnt drain
  }

  // ---- epilogue: scale by 1/l, LDS transpose, coalesced store ----
  float li = 1.f / o_l[0];
#pragma unroll
  for (int dt = 0; dt < 4; ++dt)
#pragma unroll
    for (int i = 0; i < 16; ++i) o[dt][i] *= li;
  const int qb = w * 32 + l5;
#pragma unroll
  for (int dt = 0; dt < 4; ++dt) {
#pragma unroll
    for (int rg = 0; rg < 4; ++rg) {
      int d0 = dt * 32 + rg * 8 + hi * 4;
      unsigned w0 = cvtpk(o[dt][rg * 4 + 0], o[dt][rg * 4 + 1]);
      unsigned w1 = cvtpk(o[dt][rg * 4 + 2], o[dt][rg * 4 + 3]);
      int lin = qb * 256 + d0 * 2;
      int phys = lin ^ ((qb & 7) << 4);
      *reinterpret_cast<uint2*>(lds + phys) = make_uint2(w0, w1);
    }
  }
  __syncthreads();
  const int qr = tid >> 4, c16 = tid & 15;
#pragma unroll
  for (int it = 0; it < 8; ++it) {
    int q = qr + it * 16;
    int phys = (q * 256 + c16 * 16) ^ ((q & 7) << 4);
    s16x8 v = *reinterpret_cast<const s16x8*>(lds + phys);
    *reinterpret_cast<s16x8*>(Ao + ((size_t)(b * 2048 + qbk * 128 + q)) * 2048 + h * 128 + c16 * 8) = v;
  }
}

extern "C" void kernel_launch(void* const* d_in, const int* in_sizes, int n_in,
                              void* d_out, int out_size, void* d_ws, size_t ws_size,
                              hipStream_t stream) {
  const float* x      = (const float*)d_in[0];
  const float* past_k = (const float*)d_in[1];
  const float* past_v = (const float*)d_in[2];
  const float* Wq = (const float*)d_in[3];
  const float* bq = (const float*)d_in[4];
  const float* Wk = (const float*)d_in[5];
  const float* bk = (const float*)d_in[6];
  const float* Wv = (const float*)d_in[7];
  const float* bv = (const float*)d_in[8];
  const float* Wo = (const float*)d_in[9];
  const float* bo = (const float*)d_in[10];
  float* out = (float*)d_out;

  char* ws = (char*)d_ws;
  u16* xb   = (u16*)(ws);                    // x bf16 [4096,2048]; reused as ao after qkv
  u16* wqb  = (u16*)(ws + 16777216);
  u16* wkb  = (u16*)(ws + 25165824);
  u16* wvb  = (u16*)(ws + 33554432);
  u16* wob  = (u16*)(ws + 41943040);
  u16* kc   = (u16*)(ws + 50331648);         // K cache [B,H,4096,128]
  u16* qbuf = (u16*)(ws + 83886080);         // Q [B,H,2048,128]
  u16* vn   = (u16*)(ws + 100663296);        // V new [B,H,2048,128]
  u16* vt   = (u16*)(ws + 117440512);        // V^T [B,H,128,4096]
  u16* ao   = xb;

  cvt_all<<<2048, 256, 0, stream>>>(x, Wq, Wk, Wv, Wo, past_k, xb, wqb, wkb, wvb, wob, kc);
  transpose_past_v<<<dim3(32, 32), 256, 0, stream>>>(past_v, vt);
  qkv_gemm<<<dim3(32, 48), 256, 0, stream>>>(xb, wqb, wkb, wvb, bq, bk, bv, qbuf, kc, vn);
  transpose_new_v<<<dim3(32, 32), 256, 0, stream>>>(vn, vt);
  attn_kernel<<<dim3(32, 16), 256, 0, stream>>>(qbuf, kc, vt, ao);
  proj_gemm<<<dim3(32, 16), 256, 0, stream>>>(ao, wob, bo, out);
}